// Round 3
// baseline (280.880 us; speedup 1.0000x reference)
//
#include <hip/hip_runtime.h>

static constexpr int BLOCK = 64;             // ONE wave per block: no barriers at all
static constexpr int SPT   = 4;              // samples per lane per tile
static constexpr int SPB   = BLOCK * SPT;    // 256 samples per tile
static constexpr int F4PT  = SPB * 3 / 4;    // 192 float4 per array per tile (3 gload_lds/lane)
static constexpr int GRID0 = 4096;           // 32768 tiles / 4096 = 8 contiguous tiles per wave

__device__ __forceinline__ float sample_contrib(float l0, float l1, float l2,
                                                float t0, float t1, float t2,
                                                float c, int lab) {
    float temp;
    if (c > 0.9f)      temp = 1.5f;
    else if (c > 0.6f) temp = 2.0f;
    else               temp = fminf(2.5f + (0.6f - c) * 2.0f, 3.0f);
    float invT = 1.0f / temp;

    float a0 = l0 * invT, a1 = l1 * invT, a2 = l2 * invT;
    float m  = fmaxf(a0, fmaxf(a1, a2));
    float s  = __expf(a0 - m) + __expf(a1 - m) + __expf(a2 - m);
    float lse = __logf(s) + m;

    float tlogt = t0 * __logf(t0) + t1 * __logf(t1) + t2 * __logf(t2);
    float ta    = t0 * a0 + t1 * a1 + t2 * a2;
    float kl    = tlogt - ta + lse;

    float m2 = fmaxf(l0, fmaxf(l1, l2));
    float s2 = __expf(l0 - m2) + __expf(l1 - m2) + __expf(l2 - m2);
    float lse2 = __logf(s2) + m2;
    float ll = (lab == 0) ? l0 : ((lab == 1) ? l1 : l2);
    float ce = lse2 - ll;

    return 0.5f * kl + 0.5f * ce;
}

// Barrier-free async pipeline. Each block is ONE wave with a private
// double-buffered LDS slice; correctness needs only wave-local ordering, which
// counted s_waitcnt vmcnt(N) provides (global_load_lds increments vmcnt).
// Every wave is an independent stream: 13 blocks/CU resident, each with one
// 16 KB tile prefetch permanently in flight, reading 8 contiguous tiles.
__global__ __launch_bounds__(BLOCK) void adl_main(
    const float4* __restrict__ l4,
    const int*    __restrict__ hard,
    const float4* __restrict__ s4,
    const float*  __restrict__ conf,
    double*       __restrict__ ws_sum,
    int nt, long long B)
{
    __shared__ float ldsL[2][SPB * 3];   // 2 x 3072 B
    __shared__ float ldsS[2][SPB * 3];   // 2 x 3072 B   (12.3 KB total)

    const int lane = threadIdx.x;        // 0..63
    float part = 0.0f;

    // 14 vmem ops per STAGE: 3+3 global_load_lds (16 B/lane) + 4 conf + 4 hard.
#define STAGE(BUF, TILE, CF, LB)                                                   \
    do {                                                                           \
        const float4* gl_ = l4 + (size_t)(TILE) * F4PT;                            \
        const float4* gs_ = s4 + (size_t)(TILE) * F4PT;                            \
        _Pragma("unroll")                                                          \
        for (int k = 0; k < 3; ++k)                                                \
            __builtin_amdgcn_global_load_lds(                                      \
                (const __attribute__((address_space(1))) void*)(gl_ + k * BLOCK + lane), \
                (__attribute__((address_space(3))) void*)(&ldsL[BUF][(k * BLOCK + lane) * 4]), \
                16, 0, 0);                                                         \
        _Pragma("unroll")                                                          \
        for (int k = 0; k < 3; ++k)                                                \
            __builtin_amdgcn_global_load_lds(                                      \
                (const __attribute__((address_space(1))) void*)(gs_ + k * BLOCK + lane), \
                (__attribute__((address_space(3))) void*)(&ldsS[BUF][(k * BLOCK + lane) * 4]), \
                16, 0, 0);                                                         \
        long long sb_ = (long long)(TILE) * SPB;                                   \
        _Pragma("unroll")                                                          \
        for (int j = 0; j < SPT; ++j) {                                            \
            CF[j] = conf[sb_ + j * BLOCK + lane];                                  \
            LB[j] = hard[sb_ + j * BLOCK + lane];                                  \
        }                                                                          \
    } while (0)

    // Wait until only the newest 14 vmem ops remain outstanding -> the previous
    // tile's loads (incl. its LDS writes) are complete. Wave-local, no barrier.
#define WAIT14() asm volatile("s_waitcnt vmcnt(14)" ::: "memory")
#define WAIT0()  asm volatile("s_waitcnt vmcnt(0)"  ::: "memory")

#define COMPUTE(BUF, CF, LB)                                                       \
    do {                                                                           \
        _Pragma("unroll")                                                          \
        for (int j = 0; j < SPT; ++j) {                                            \
            int s_ = j * BLOCK + lane;  /* word addr 3*lane+c: gcd(3,32)=1 */      \
            part += sample_contrib(ldsL[BUF][3 * s_], ldsL[BUF][3 * s_ + 1],       \
                                   ldsL[BUF][3 * s_ + 2],                          \
                                   ldsS[BUF][3 * s_], ldsS[BUF][3 * s_ + 1],       \
                                   ldsS[BUF][3 * s_ + 2], CF[j], LB[j]);           \
        }                                                                          \
    } while (0)

    // contiguous tile range per block: q tiles each, remainder to low blocks
    const int G = gridDim.x;
    int q = nt / G, r = nt % G;
    int b = blockIdx.x;
    int cnt = q + (b < r ? 1 : 0);
    int t0  = b * q + (b < r ? b : r);

    float cfA[SPT], cfB[SPT];
    int   lbA[SPT], lbB[SPT];

    if (cnt > 0) {
        STAGE(0, t0, cfA, lbA);
        int i = 0;
        while (true) {
            // phase A: compute buf0 (tile t0+i), prefetch buf1 (tile t0+i+1)
            if (i + 1 < cnt) { STAGE(1, t0 + i + 1, cfB, lbB); WAIT14(); }
            else             { WAIT0(); }
            __builtin_amdgcn_sched_barrier(0);
            COMPUTE(0, cfA, lbA);
            if (++i >= cnt) break;
            // phase B: compute buf1, prefetch buf0
            if (i + 1 < cnt) { STAGE(0, t0 + i + 1, cfA, lbA); WAIT14(); }
            else             { WAIT0(); }
            __builtin_amdgcn_sched_barrier(0);
            COMPUTE(1, cfB, lbB);
            if (++i >= cnt) break;
        }
    }

    // remainder samples (B % SPB != 0; not taken for B = 8388608)
    long long done = (long long)nt * SPB;
    if (done < B) {
        const float* lf = (const float*)l4;
        const float* sf = (const float*)s4;
        for (long long s = done + (long long)b * BLOCK + lane; s < B;
             s += (long long)G * BLOCK)
            part += sample_contrib(lf[3 * s], lf[3 * s + 1], lf[3 * s + 2],
                                   sf[3 * s], sf[3 * s + 1], sf[3 * s + 2],
                                   conf[s], hard[s]);
    }

#undef STAGE
#undef WAIT14
#undef WAIT0
#undef COMPUTE

    // wave-level reduction, one atomic per wave (no LDS, no syncthreads)
    double acc = (double)part;
#pragma unroll
    for (int off = 32; off > 0; off >>= 1)
        acc += __shfl_down(acc, off, 64);
    if (lane == 0)
        atomicAdd(ws_sum, acc);
}

__global__ void adl_finalize(const double* __restrict__ ws,
                             float* __restrict__ out, double invB) {
    out[0] = (float)(ws[0] * invB);
}

extern "C" void kernel_launch(void* const* d_in, const int* in_sizes, int n_in,
                              void* d_out, int out_size, void* d_ws, size_t ws_size,
                              hipStream_t stream) {
    const float* logits = (const float*)d_in[0];
    const int*   hard   = (const int*)d_in[1];
    const float* soft   = (const float*)d_in[2];
    const float* conf   = (const float*)d_in[3];

    long long B = in_sizes[1];      // batch size
    int nt = (int)(B / SPB);        // 32768 full tiles for B = 8388608

    double* ws = (double*)d_ws;
    hipMemsetAsync(ws, 0, sizeof(double), stream);

    int grid = GRID0;
    if (nt < grid) grid = (nt > 0) ? nt : 1;   // nt=32768 -> 4096 blocks, 8 tiles each

    adl_main<<<grid, BLOCK, 0, stream>>>((const float4*)logits, hard,
                                         (const float4*)soft, conf,
                                         ws, nt, B);
    adl_finalize<<<1, 1, 0, stream>>>(ws, (float*)d_out, 1.0 / (double)B);
}

// Round 4
// 246.913 us; speedup vs baseline: 1.1376x; 1.1376x over previous
//
#include <hip/hip_runtime.h>

static constexpr int BLOCK = 256;
static constexpr int SPT   = 4;              // samples per thread per tile
static constexpr int SPB   = BLOCK * SPT;    // 1024 samples per tile
static constexpr int F4PT  = SPB * 3 / 4;    // 768 float4 per array per tile
static constexpr int GRID0 = 2048;           // 8192 tiles / 2048 = 4 tiles/block exactly

__device__ __forceinline__ float sample_contrib(float l0, float l1, float l2,
                                                float t0, float t1, float t2,
                                                float c, int lab) {
    float temp;
    if (c > 0.9f)      temp = 1.5f;
    else if (c > 0.6f) temp = 2.0f;
    else               temp = fminf(2.5f + (0.6f - c) * 2.0f, 3.0f);
    float invT = 1.0f / temp;

    float a0 = l0 * invT, a1 = l1 * invT, a2 = l2 * invT;
    float m  = fmaxf(a0, fmaxf(a1, a2));
    float s  = __expf(a0 - m) + __expf(a1 - m) + __expf(a2 - m);
    float lse = __logf(s) + m;

    float tlogt = t0 * __logf(t0) + t1 * __logf(t1) + t2 * __logf(t2);
    float ta    = t0 * a0 + t1 * a1 + t2 * a2;
    float kl    = tlogt - ta + lse;

    float m2 = fmaxf(l0, fmaxf(l1, l2));
    float s2 = __expf(l0 - m2) + __expf(l1 - m2) + __expf(l2 - m2);
    float lse2 = __logf(s2) + m2;
    float ll = (lab == 0) ? l0 : ((lab == 1) ? l1 : l2);
    float ce = lse2 - ll;

    return 0.5f * kl + 0.5f * ce;
}

// Round-2 pipelined double-buffer kernel, ONE change: the six global_load_lds
// for logits/soft carry aux=2 (CPol NT bit on gfx950 -> "nt" cache policy).
// Theory: working set is EXACTLY 256 MiB = Infinity Cache size; cyclic restream
// steady-states at ~50% hit, so HBM serves ~131 MB of pseudo-randomly
// interleaved evicted lines at 1.3 TB/s (row-buffer thrash). NT streams the two
// big arrays (201 MB) past the MALL -> contiguous HBM misses at full rate, and
// leaves conf/hard (67 MB) L3-resident.
__global__ __launch_bounds__(BLOCK) void adl_main(
    const float4* __restrict__ l4,
    const int*    __restrict__ hard,
    const float4* __restrict__ s4,
    const float*  __restrict__ conf,
    double*       __restrict__ ws_sum,
    int nt, long long B)
{
    __shared__ float ldsL[2][SPB * 3];   // 2 x 12288 B
    __shared__ float ldsS[2][SPB * 3];   // 2 x 12288 B  (total 48 KiB)

    const int t   = threadIdx.x;
    const int bid = blockIdx.x;
    const int G   = gridDim.x;
    float part = 0.0f;

    // 14 vmem ops per STAGE: 6 global_load_lds (NT) + 4 conf + 4 hard (cached).
#define STAGE(BUF, TILE, CF, LB)                                                   \
    do {                                                                           \
        const float4* gl_ = l4 + (size_t)(TILE) * F4PT;                            \
        const float4* gs_ = s4 + (size_t)(TILE) * F4PT;                            \
        _Pragma("unroll")                                                          \
        for (int k = 0; k < 3; ++k)                                                \
            __builtin_amdgcn_global_load_lds(                                      \
                (const __attribute__((address_space(1))) void*)(gl_ + k * BLOCK + t), \
                (__attribute__((address_space(3))) void*)(&ldsL[BUF][(k * BLOCK + t) * 4]), \
                16, 0, 2 /* CPol NT */);                                           \
        _Pragma("unroll")                                                          \
        for (int k = 0; k < 3; ++k)                                                \
            __builtin_amdgcn_global_load_lds(                                      \
                (const __attribute__((address_space(1))) void*)(gs_ + k * BLOCK + t), \
                (__attribute__((address_space(3))) void*)(&ldsS[BUF][(k * BLOCK + t) * 4]), \
                16, 0, 2 /* CPol NT */);                                           \
        long long sb_ = (long long)(TILE) * SPB;                                   \
        _Pragma("unroll")                                                          \
        for (int j = 0; j < SPT; ++j) {                                            \
            CF[j] = conf[sb_ + j * BLOCK + t];                                     \
            LB[j] = hard[sb_ + j * BLOCK + t];                                     \
        }                                                                          \
    } while (0)

#define WAIT14() asm volatile("s_waitcnt vmcnt(14)" ::: "memory")
#define WAIT0()  asm volatile("s_waitcnt vmcnt(0)"  ::: "memory")
#define BAR()                                    \
    do {                                         \
        __builtin_amdgcn_s_barrier();            \
        __builtin_amdgcn_sched_barrier(0);       \
    } while (0)

#define COMPUTE(BUF, CF, LB)                                                       \
    do {                                                                           \
        _Pragma("unroll")                                                          \
        for (int j = 0; j < SPT; ++j) {                                            \
            int s_ = j * BLOCK + t;  /* word addr 3t+c: gcd(3,32)=1 -> 2-way, free */ \
            part += sample_contrib(ldsL[BUF][3 * s_], ldsL[BUF][3 * s_ + 1],       \
                                   ldsL[BUF][3 * s_ + 2],                          \
                                   ldsS[BUF][3 * s_], ldsS[BUF][3 * s_ + 1],       \
                                   ldsS[BUF][3 * s_ + 2], CF[j], LB[j]);           \
        }                                                                          \
    } while (0)

    // tiles for this block: bid, bid+G, bid+2G, ...  (uniform within block)
    int nb = (bid < nt) ? ((nt - 1 - bid) / G + 1) : 0;

    float cfA[SPT], cfB[SPT];
    int   lbA[SPT], lbB[SPT];

    if (nb > 0) {
        STAGE(0, bid, cfA, lbA);
        int i = 0;
        while (true) {
            // ---- phase A: compute buf0 (tile i), prefetch into buf1 (tile i+1)
            {
                bool hn = (i + 1 < nb);
                if (hn) { STAGE(1, bid + (i + 1) * G, cfB, lbB); WAIT14(); }
                else    { WAIT0(); }
                BAR();
                COMPUTE(0, cfA, lbA);
                BAR();
            }
            if (++i >= nb) break;
            // ---- phase B: compute buf1 (tile i), prefetch into buf0 (tile i+1)
            {
                bool hn = (i + 1 < nb);
                if (hn) { STAGE(0, bid + (i + 1) * G, cfA, lbA); WAIT14(); }
                else    { WAIT0(); }
                BAR();
                COMPUTE(1, cfB, lbB);
                BAR();
            }
            if (++i >= nb) break;
        }
    }

    // remainder samples (B not a multiple of SPB; not taken for B = 8388608)
    long long done = (long long)nt * SPB;
    if (done < B) {
        const float* lf = (const float*)l4;
        const float* sf = (const float*)s4;
        for (long long s = done + (long long)bid * BLOCK + t; s < B;
             s += (long long)G * BLOCK)
            part += sample_contrib(lf[3 * s], lf[3 * s + 1], lf[3 * s + 2],
                                   sf[3 * s], sf[3 * s + 1], sf[3 * s + 2],
                                   conf[s], hard[s]);
    }

#undef STAGE
#undef WAIT14
#undef WAIT0
#undef BAR
#undef COMPUTE

    // block reduction -> one double atomic
    double acc = (double)part;
#pragma unroll
    for (int off = 32; off > 0; off >>= 1)
        acc += __shfl_down(acc, off, 64);

    __shared__ double red[BLOCK / 64];
    int lane = t & 63;
    int wid  = t >> 6;
    if (lane == 0) red[wid] = acc;
    __syncthreads();
    if (t == 0) {
        double s = 0.0;
#pragma unroll
        for (int i = 0; i < BLOCK / 64; ++i) s += red[i];
        atomicAdd(ws_sum, s);
    }
}

__global__ void adl_finalize(const double* __restrict__ ws,
                             float* __restrict__ out, double invB) {
    out[0] = (float)(ws[0] * invB);
}

extern "C" void kernel_launch(void* const* d_in, const int* in_sizes, int n_in,
                              void* d_out, int out_size, void* d_ws, size_t ws_size,
                              hipStream_t stream) {
    const float* logits = (const float*)d_in[0];
    const int*   hard   = (const int*)d_in[1];
    const float* soft   = (const float*)d_in[2];
    const float* conf   = (const float*)d_in[3];

    long long B = in_sizes[1];      // batch size
    int nt = (int)(B / SPB);        // 8192 full tiles for B = 8388608

    double* ws = (double*)d_ws;
    hipMemsetAsync(ws, 0, sizeof(double), stream);

    int grid = GRID0;
    if (nt < grid) grid = (nt > 0) ? nt : 1;   // nt=8192 -> 2048 blocks, 4 tiles each

    adl_main<<<grid, BLOCK, 0, stream>>>((const float4*)logits, hard,
                                         (const float4*)soft, conf,
                                         ws, nt, B);
    adl_finalize<<<1, 1, 0, stream>>>(ws, (float*)d_out, 1.0 / (double)B);
}